// Round 5
// baseline (498.203 us; speedup 1.0000x reference)
//
#include <hip/hip_runtime.h>
#include <stdint.h>

#define NTOK 16384
#define KVB 64

typedef __attribute__((ext_vector_type(8))) short short8;
typedef __attribute__((ext_vector_type(4))) float f32x4;

// round-to-nearest-even f32 -> bf16 (bit pattern as short)
__device__ __forceinline__ short f2bf_rne(float f) {
  union { float f; unsigned u; } a; a.f = f;
  unsigned r = a.u + 0x7fffu + ((a.u >> 16) & 1u);
  return (short)(r >> 16);
}

// compiler-managed v_exp_f32 (raw asm bypasses the trans-op hazard recognizer)
__device__ __forceinline__ float fast_exp2(float x) {
#if __has_builtin(__builtin_amdgcn_exp2f)
  return __builtin_amdgcn_exp2f(x);
#else
  return exp2f(x);
#endif
}

__device__ __forceinline__ unsigned cvt_pk_bf16(float lo, float hi) {
  unsigned r;
  asm("v_cvt_pk_bf16_f32 %0, %1, %2" : "=v"(r) : "v"(lo), "v"(hi));
  return r;
}

// ---------------- projection: Q, K  ([N][8] bf16 rows) ----------------
// blockIdx.y: 0 -> Q, 1 -> K (K pre-scaled by 1/ln2 for v_exp_f32 = 2^x).
__global__ __launch_bounds__(256) void proj_qk_kernel(
    const float* __restrict__ x,
    const float* __restrict__ Wq, const float* __restrict__ bq,
    const float* __restrict__ Wk, const float* __restrict__ bk,
    short* __restrict__ Qp, short* __restrict__ Kp)
{
  const int which = blockIdx.y;
  const float* W    = which ? Wk : Wq;
  const float* bias = which ? bk : bq;
  short* Out        = which ? Kp : Qp;
  const float scale = which ? 1.44269504f : 1.0f;

  __shared__ float sW[512], sb[8];
  const int tid = threadIdx.x;
  for (int i = tid; i < 512; i += 256) sW[i] = W[i];
  if (tid < 8) sb[tid] = bias[tid];
  __syncthreads();

  const int n = blockIdx.x * 256 + tid;
  float xv[64];
#pragma unroll
  for (int c = 0; c < 64; ++c) xv[c] = x[c * NTOK + n];

  short8 ov;
#pragma unroll
  for (int d = 0; d < 8; ++d) {
    float a = sb[d];
#pragma unroll
    for (int c = 0; c < 64; c += 4) {
      f32x4 wv = *reinterpret_cast<const f32x4*>(&sW[d * 64 + c]);
      a += wv[0]*xv[c] + wv[1]*xv[c+1] + wv[2]*xv[c+2] + wv[3]*xv[c+3];
    }
    ov[d] = f2bf_rne(a * scale);
  }
  *reinterpret_cast<short8*>(Out + (size_t)n * 8) = ov;
}

// ---------------- projection: V^T with per-32-block slot permutation ----
// j(s) = ((s&12)<<1) | (s&3) | ((s&16)>>2)  maps key slot -> A-frag K-pos.
__global__ __launch_bounds__(256) void proj_v_kernel(
    const float* __restrict__ x,
    const float* __restrict__ Wv, const float* __restrict__ bv,
    short* __restrict__ Vp)
{
  __shared__ float sW[1024], sb[16];
  const int tid = threadIdx.x;
  const int sp = blockIdx.y;                 // channel split 0..3 (16 ch each)
  for (int i = tid; i < 1024; i += 256) sW[i] = Wv[sp * 1024 + i];
  if (tid < 16) sb[tid] = bv[sp * 16 + tid];
  __syncthreads();

  const int n = blockIdx.x * 256 + tid;
  float xv[64];
#pragma unroll
  for (int c = 0; c < 64; ++c) xv[c] = x[c * NTOK + n];

  const int s = n & 31;
  const int j = ((s & 12) << 1) | (s & 3) | ((s & 16) >> 2);
  const int jn = (n & ~31) | j;

#pragma unroll
  for (int d = 0; d < 16; ++d) {
    float a = sb[d];
#pragma unroll
    for (int c = 0; c < 64; c += 4) {
      f32x4 wv = *reinterpret_cast<const f32x4*>(&sW[d * 64 + c]);
      a += wv[0]*xv[c] + wv[1]*xv[c+1] + wv[2]*xv[c+2] + wv[3]*xv[c+3];
    }
    Vp[(size_t)(sp * 16 + d) * NTOK + jn] = f2bf_rne(a);
  }
}

// ---------------- fused attention, split-K, no LDS ----------------------
// NF = q-fragments per wave (16 rows each). K/V fragments load directly from
// global (L2-resident) into registers; V frags are reused across the NF
// q-fragments. Partials additive (no max subtraction -> no LSE merge).
// part layout: [s][q global][c] (NF-agnostic), lsums: [s][q global].
template<int NF>
__global__ __launch_bounds__(256, 4) void attn_split_kernel(
    const short* __restrict__ Qp, const short* __restrict__ Kp,
    const short* __restrict__ Vp,
    float* __restrict__ part, float* __restrict__ lsums, int splits)
{
  const int tid  = threadIdx.x;
  const int w    = tid >> 6;
  const int lane = tid & 63;
  const int g    = lane >> 4;
  const int qi   = lane & 15;
  const int s    = blockIdx.x;
  const int qw   = blockIdx.y * 4 + w;
  const int q0   = qw * (NF * 16);

  const short8 zero8 = {0,0,0,0,0,0,0,0};
  const f32x4  zf    = {0.f,0.f,0.f,0.f};

  // Q fragments: B[d=8g+e][q=qi]; zero for g!=0 (pad d 8->32)
  short8 qf[NF];
#pragma unroll
  for (int f = 0; f < NF; ++f)
    qf[f] = (g == 0)
        ? *reinterpret_cast<const short8*>(Qp + (size_t)(q0 + 16*f + qi) * 8)
        : zero8;

  f32x4 acc[NF][4];
#pragma unroll
  for (int f = 0; f < NF; ++f)
#pragma unroll
    for (int cb = 0; cb < 4; ++cb) acc[f][cb] = zf;
  float lsum[NF];
#pragma unroll
  for (int f = 0; f < NF; ++f) lsum[f] = 0.f;

  const int kvlen = NTOK / splits;
  const int kv_lo = s * kvlen;

  const short* krow = Kp + (size_t)qi * 8;   // +16B per key row
  const short* vrow[4];
#pragma unroll
  for (int cb = 0; cb < 4; ++cb)
    vrow[cb] = Vp + (size_t)(cb * 16 + qi) * NTOK + 8 * g;

  for (int kv0 = kv_lo; kv0 < kv_lo + kvlen; kv0 += KVB) {
    // issue all 12 tile loads upfront; latency hides under QK^T + exp
    short8 kf[4], vf[2][4];
#pragma unroll
    for (int t = 0; t < 4; ++t)
      kf[t] = *reinterpret_cast<const short8*>(krow + (size_t)(kv0 + 16*t) * 8);
#pragma unroll
    for (int h = 0; h < 2; ++h)
#pragma unroll
      for (int cb = 0; cb < 4; ++cb)
        vf[h][cb] = *reinterpret_cast<const short8*>(vrow[cb] + kv0 + 32*h);

#pragma unroll
    for (int h = 0; h < 2; ++h) {
      union { short8 s8; unsigned u32[4]; } pa[NF];
#pragma unroll
      for (int f = 0; f < NF; ++f) {
        f32x4 sv0 = __builtin_amdgcn_mfma_f32_16x16x32_bf16(kf[2*h],   qf[f], zf, 0, 0, 0);
        f32x4 sv1 = __builtin_amdgcn_mfma_f32_16x16x32_bf16(kf[2*h+1], qf[f], zf, 0, 0, 0);
        float e00 = fast_exp2(sv0[0]), e01 = fast_exp2(sv0[1]);
        float e02 = fast_exp2(sv0[2]), e03 = fast_exp2(sv0[3]);
        float e10 = fast_exp2(sv1[0]), e11 = fast_exp2(sv1[1]);
        float e12 = fast_exp2(sv1[2]), e13 = fast_exp2(sv1[3]);
        lsum[f] += ((e00 + e01) + (e02 + e03)) + ((e10 + e11) + (e12 + e13));
        pa[f].u32[0] = cvt_pk_bf16(e00, e01);
        pa[f].u32[1] = cvt_pk_bf16(e02, e03);
        pa[f].u32[2] = cvt_pk_bf16(e10, e11);
        pa[f].u32[3] = cvt_pk_bf16(e12, e13);
      }
#pragma unroll
      for (int cb = 0; cb < 4; ++cb)
#pragma unroll
        for (int f = 0; f < NF; ++f)
          acc[f][cb] = __builtin_amdgcn_mfma_f32_16x16x32_bf16(pa[f].s8, vf[h][cb], acc[f][cb], 0, 0, 0);
    }
  }

  // partial row denominators: combine the 4 g-groups
#pragma unroll
  for (int f = 0; f < NF; ++f) {
    float l = lsum[f];
    l += __shfl_xor(l, 16);
    l += __shfl_xor(l, 32);
    if (lane < 16)
      lsums[(size_t)s * NTOK + q0 + 16*f + lane] = l;
  }

  // partial O, q-major [q][64c] at absolute q
  float* pp = part + ((size_t)s * NTOK + q0) * 64;
#pragma unroll
  for (int f = 0; f < NF; ++f)
#pragma unroll
    for (int cb = 0; cb < 4; ++cb)
#pragma unroll
      for (int r = 0; r < 4; ++r)
        pp[(16*f + 4*g + r) * 64 + cb * 16 + qi] = acc[f][cb][r];
}

// ---------------- reduce: sum partials, normalize, gamma*O + x ----------
__global__ __launch_bounds__(256) void reduce_kernel(
    const float* __restrict__ part, const float* __restrict__ lsums,
    const float* __restrict__ x, const float* __restrict__ gamma,
    float* __restrict__ out, int splits)
{
  __shared__ float tile[64][65];
  __shared__ float linv[64];
  const int tid = threadIdx.x;
  const int qb  = blockIdx.x;

  // phase 1: coalesced q-major reads, sum over splits
  {
    const int qloc = tid >> 2, c0 = (tid & 3) * 16;
    f32x4 a[4] = {{0,0,0,0},{0,0,0,0},{0,0,0,0},{0,0,0,0}};
    float ls = 0.f;
    for (int s = 0; s < splits; ++s) {
      const float* p = part + ((size_t)s * NTOK + qb * 64 + qloc) * 64 + c0;
#pragma unroll
      for (int j = 0; j < 4; ++j)
        a[j] += *reinterpret_cast<const f32x4*>(p + 4 * j);
      if ((tid & 3) == 0)
        ls += lsums[(size_t)s * NTOK + qb * 64 + qloc];
    }
#pragma unroll
    for (int j = 0; j < 4; ++j)
#pragma unroll
      for (int e = 0; e < 4; ++e)
        tile[qloc][c0 + 4 * j + e] = a[j][e];
    if ((tid & 3) == 0) linv[qloc] = 1.f / ls;
  }
  __syncthreads();

  // phase 2: c-major writes (transposed via LDS)
  const int c = tid >> 2, qs = (tid & 3) * 16;
  const float gam = gamma[0];
#pragma unroll
  for (int i = 0; i < 16; ++i) {
    const int q = qs + i;
    const size_t idx = (size_t)c * NTOK + qb * 64 + q;
    out[idx] = gam * tile[q][c] * linv[q] + x[idx];
  }
}

extern "C" void kernel_launch(void* const* d_in, const int* in_sizes, int n_in,
                              void* d_out, int out_size, void* d_ws, size_t ws_size,
                              hipStream_t stream) {
  const float* x     = (const float*)d_in[0];
  const float* Wq    = (const float*)d_in[1];
  const float* bq    = (const float*)d_in[2];
  const float* Wk    = (const float*)d_in[3];
  const float* bk    = (const float*)d_in[4];
  const float* Wv    = (const float*)d_in[5];
  const float* bv    = (const float*)d_in[6];
  const float* gamma = (const float*)d_in[7];
  float* out = (float*)d_out;

  short* Qp = (short*)d_ws;                 // [N][8]  bf16  (256 KB)
  short* Kp = Qp + (size_t)NTOK * 8;        // [N][8]  bf16  (256 KB)
  short* Vp = Kp + (size_t)NTOK * 8;        // [64][N] bf16  (2 MB), permuted cols
  float* part  = (float*)(Vp + (size_t)64 * NTOK);       // [s][q][64c]

  const size_t base_bytes = (size_t)NTOK * 8 * 2 * 2 + (size_t)64 * NTOK * 2;
  auto fits = [&](int sp) {
    return base_bytes + (size_t)sp * NTOK * 64 * 4 + (size_t)sp * NTOK * 4 <= ws_size;
  };

  // target >= 4096 waves (4/SIMD): NF=4 needs splits=16; NF=2 needs splits=8.
  int NF, splits;
  if (fits(16))      { NF = 4; splits = 16; }
  else if (fits(8))  { NF = 2; splits = 8;  }
  else               { NF = 2; splits = 4; if (!fits(4)) splits = 2; }

  float* lsums = part + (size_t)splits * NTOK * 64;

  proj_qk_kernel<<<dim3(NTOK / 256, 2), 256, 0, stream>>>(x, Wq, bq, Wk, bk, Qp, Kp);
  proj_v_kernel<<<dim3(NTOK / 256, 4), 256, 0, stream>>>(x, Wv, bv, Vp);
  const int nqw = NTOK / (NF * 16);
  if (NF == 4)
    attn_split_kernel<4><<<dim3(splits, nqw / 4), 256, 0, stream>>>(Qp, Kp, Vp, part, lsums, splits);
  else
    attn_split_kernel<2><<<dim3(splits, nqw / 4), 256, 0, stream>>>(Qp, Kp, Vp, part, lsums, splits);
  reduce_kernel<<<NTOK / 64, 256, 0, stream>>>(part, lsums, x, gamma, out, splits);
}

// Round 6
// 106.340 us; speedup vs baseline: 4.6850x; 4.6850x over previous
//
#include <hip/hip_runtime.h>
#include <stdint.h>

#define NTOK 16384
#define KVB 64

typedef __attribute__((ext_vector_type(8))) short short8;
typedef __attribute__((ext_vector_type(4))) float f32x4;

// round-to-nearest-even f32 -> bf16 (bit pattern as short)
__device__ __forceinline__ short f2bf_rne(float f) {
  union { float f; unsigned u; } a; a.f = f;
  unsigned r = a.u + 0x7fffu + ((a.u >> 16) & 1u);
  return (short)(r >> 16);
}

// compiler-managed v_exp_f32 (raw asm bypasses the trans-op hazard recognizer)
__device__ __forceinline__ float fast_exp2(float x) {
#if __has_builtin(__builtin_amdgcn_exp2f)
  return __builtin_amdgcn_exp2f(x);
#else
  return exp2f(x);
#endif
}

__device__ __forceinline__ unsigned cvt_pk_bf16(float lo, float hi) {
  unsigned r;
  asm("v_cvt_pk_bf16_f32 %0, %1, %2" : "=v"(r) : "v"(lo), "v"(hi));
  return r;
}

// ---------------- projection: Q, K  ([N][8] bf16 rows) ----------------
// blockIdx.y: 0 -> Q, 1 -> K (K pre-scaled by 1/ln2 for v_exp_f32 = 2^x).
__global__ __launch_bounds__(256) void proj_qk_kernel(
    const float* __restrict__ x,
    const float* __restrict__ Wq, const float* __restrict__ bq,
    const float* __restrict__ Wk, const float* __restrict__ bk,
    short* __restrict__ Qp, short* __restrict__ Kp)
{
  const int which = blockIdx.y;
  const float* W    = which ? Wk : Wq;
  const float* bias = which ? bk : bq;
  short* Out        = which ? Kp : Qp;
  const float scale = which ? 1.44269504f : 1.0f;

  __shared__ float sW[512], sb[8];
  const int tid = threadIdx.x;
  for (int i = tid; i < 512; i += 256) sW[i] = W[i];
  if (tid < 8) sb[tid] = bias[tid];
  __syncthreads();

  const int n = blockIdx.x * 256 + tid;
  float xv[64];
#pragma unroll
  for (int c = 0; c < 64; ++c) xv[c] = x[c * NTOK + n];

  short8 ov;
#pragma unroll
  for (int d = 0; d < 8; ++d) {
    float a = sb[d];
#pragma unroll
    for (int c = 0; c < 64; c += 4) {
      f32x4 wv = *reinterpret_cast<const f32x4*>(&sW[d * 64 + c]);
      a += wv[0]*xv[c] + wv[1]*xv[c+1] + wv[2]*xv[c+2] + wv[3]*xv[c+3];
    }
    ov[d] = f2bf_rne(a * scale);
  }
  *reinterpret_cast<short8*>(Out + (size_t)n * 8) = ov;
}

// ---------------- projection: V^T with per-32-block slot permutation ----
// j(s) = ((s&12)<<1) | (s&3) | ((s&16)>>2)  maps key slot -> A-frag K-pos.
__global__ __launch_bounds__(256) void proj_v_kernel(
    const float* __restrict__ x,
    const float* __restrict__ Wv, const float* __restrict__ bv,
    short* __restrict__ Vp)
{
  __shared__ float sW[1024], sb[16];
  const int tid = threadIdx.x;
  const int sp = blockIdx.y;                 // channel split 0..3 (16 ch each)
  for (int i = tid; i < 1024; i += 256) sW[i] = Wv[sp * 1024 + i];
  if (tid < 16) sb[tid] = bv[sp * 16 + tid];
  __syncthreads();

  const int n = blockIdx.x * 256 + tid;
  float xv[64];
#pragma unroll
  for (int c = 0; c < 64; ++c) xv[c] = x[c * NTOK + n];

  const int s = n & 31;
  const int j = ((s & 12) << 1) | (s & 3) | ((s & 16) >> 2);
  const int jn = (n & ~31) | j;

#pragma unroll
  for (int d = 0; d < 16; ++d) {
    float a = sb[d];
#pragma unroll
    for (int c = 0; c < 64; c += 4) {
      f32x4 wv = *reinterpret_cast<const f32x4*>(&sW[d * 64 + c]);
      a += wv[0]*xv[c] + wv[1]*xv[c+1] + wv[2]*xv[c+2] + wv[3]*xv[c+3];
    }
    Vp[(size_t)(sp * 16 + d) * NTOK + jn] = f2bf_rne(a);
  }
}

// ---------------- fused attention, split-K, no LDS ----------------------
// NF = q-fragments per wave (16 rows each). K/V fragments load directly from
// global (L2-resident) into registers; V frags are reused across the NF
// q-fragments. Partials additive (no max subtraction -> no LSE merge).
// part layout: [s][q global][c] (NF-agnostic), lsums: [s][q global].
// NOTE: keep min-waves at 2. (256,4) caps unified VGPR+AGPR at 128 and the
// allocator splits 64+64 -> spills acc to scratch = GBs of HBM traffic (R5).
// NF=4 compiles to 112 VGPR, which the HW runs at 4 waves/SIMD anyway.
template<int NF>
__global__ __launch_bounds__(256, 2) void attn_split_kernel(
    const short* __restrict__ Qp, const short* __restrict__ Kp,
    const short* __restrict__ Vp,
    float* __restrict__ part, float* __restrict__ lsums, int splits)
{
  const int tid  = threadIdx.x;
  const int w    = tid >> 6;
  const int lane = tid & 63;
  const int g    = lane >> 4;
  const int qi   = lane & 15;
  const int s    = blockIdx.x;
  const int qw   = blockIdx.y * 4 + w;
  const int q0   = qw * (NF * 16);

  const short8 zero8 = {0,0,0,0,0,0,0,0};
  const f32x4  zf    = {0.f,0.f,0.f,0.f};

  // Q fragments: B[d=8g+e][q=qi]; zero for g!=0 (pad d 8->32)
  short8 qf[NF];
#pragma unroll
  for (int f = 0; f < NF; ++f)
    qf[f] = (g == 0)
        ? *reinterpret_cast<const short8*>(Qp + (size_t)(q0 + 16*f + qi) * 8)
        : zero8;

  f32x4 acc[NF][4];
#pragma unroll
  for (int f = 0; f < NF; ++f)
#pragma unroll
    for (int cb = 0; cb < 4; ++cb) acc[f][cb] = zf;
  float lsum[NF];
#pragma unroll
  for (int f = 0; f < NF; ++f) lsum[f] = 0.f;

  const int kvlen = NTOK / splits;
  const int kv_lo = s * kvlen;

  const short* krow = Kp + (size_t)qi * 8;   // +16B per key row
  const short* vrow[4];
#pragma unroll
  for (int cb = 0; cb < 4; ++cb)
    vrow[cb] = Vp + (size_t)(cb * 16 + qi) * NTOK + 8 * g;

  for (int kv0 = kv_lo; kv0 < kv_lo + kvlen; kv0 += KVB) {
    // issue all 12 tile loads upfront; latency hides under QK^T + exp
    short8 kf[4], vf[2][4];
#pragma unroll
    for (int t = 0; t < 4; ++t)
      kf[t] = *reinterpret_cast<const short8*>(krow + (size_t)(kv0 + 16*t) * 8);
#pragma unroll
    for (int h = 0; h < 2; ++h)
#pragma unroll
      for (int cb = 0; cb < 4; ++cb)
        vf[h][cb] = *reinterpret_cast<const short8*>(vrow[cb] + kv0 + 32*h);

#pragma unroll
    for (int h = 0; h < 2; ++h) {
      union { short8 s8; unsigned u32[4]; } pa[NF];
#pragma unroll
      for (int f = 0; f < NF; ++f) {
        f32x4 sv0 = __builtin_amdgcn_mfma_f32_16x16x32_bf16(kf[2*h],   qf[f], zf, 0, 0, 0);
        f32x4 sv1 = __builtin_amdgcn_mfma_f32_16x16x32_bf16(kf[2*h+1], qf[f], zf, 0, 0, 0);
        float e00 = fast_exp2(sv0[0]), e01 = fast_exp2(sv0[1]);
        float e02 = fast_exp2(sv0[2]), e03 = fast_exp2(sv0[3]);
        float e10 = fast_exp2(sv1[0]), e11 = fast_exp2(sv1[1]);
        float e12 = fast_exp2(sv1[2]), e13 = fast_exp2(sv1[3]);
        lsum[f] += ((e00 + e01) + (e02 + e03)) + ((e10 + e11) + (e12 + e13));
        pa[f].u32[0] = cvt_pk_bf16(e00, e01);
        pa[f].u32[1] = cvt_pk_bf16(e02, e03);
        pa[f].u32[2] = cvt_pk_bf16(e10, e11);
        pa[f].u32[3] = cvt_pk_bf16(e12, e13);
      }
#pragma unroll
      for (int cb = 0; cb < 4; ++cb)
#pragma unroll
        for (int f = 0; f < NF; ++f)
          acc[f][cb] = __builtin_amdgcn_mfma_f32_16x16x32_bf16(pa[f].s8, vf[h][cb], acc[f][cb], 0, 0, 0);
    }
  }

  // partial row denominators: combine the 4 g-groups
#pragma unroll
  for (int f = 0; f < NF; ++f) {
    float l = lsum[f];
    l += __shfl_xor(l, 16);
    l += __shfl_xor(l, 32);
    if (lane < 16)
      lsums[(size_t)s * NTOK + q0 + 16*f + lane] = l;
  }

  // partial O, q-major [q][64c] at absolute q
  float* pp = part + ((size_t)s * NTOK + q0) * 64;
#pragma unroll
  for (int f = 0; f < NF; ++f)
#pragma unroll
    for (int cb = 0; cb < 4; ++cb)
#pragma unroll
      for (int r = 0; r < 4; ++r)
        pp[(16*f + 4*g + r) * 64 + cb * 16 + qi] = acc[f][cb][r];
}

// ---------------- reduce: sum partials, normalize, gamma*O + x ----------
__global__ __launch_bounds__(256) void reduce_kernel(
    const float* __restrict__ part, const float* __restrict__ lsums,
    const float* __restrict__ x, const float* __restrict__ gamma,
    float* __restrict__ out, int splits)
{
  __shared__ float tile[64][65];
  __shared__ float linv[64];
  const int tid = threadIdx.x;
  const int qb  = blockIdx.x;

  // phase 1: coalesced q-major reads, sum over splits
  {
    const int qloc = tid >> 2, c0 = (tid & 3) * 16;
    f32x4 a[4] = {{0,0,0,0},{0,0,0,0},{0,0,0,0},{0,0,0,0}};
    float ls = 0.f;
    for (int s = 0; s < splits; ++s) {
      const float* p = part + ((size_t)s * NTOK + qb * 64 + qloc) * 64 + c0;
#pragma unroll
      for (int j = 0; j < 4; ++j)
        a[j] += *reinterpret_cast<const f32x4*>(p + 4 * j);
      if ((tid & 3) == 0)
        ls += lsums[(size_t)s * NTOK + qb * 64 + qloc];
    }
#pragma unroll
    for (int j = 0; j < 4; ++j)
#pragma unroll
      for (int e = 0; e < 4; ++e)
        tile[qloc][c0 + 4 * j + e] = a[j][e];
    if ((tid & 3) == 0) linv[qloc] = 1.f / ls;
  }
  __syncthreads();

  // phase 2: c-major writes (transposed via LDS)
  const int c = tid >> 2, qs = (tid & 3) * 16;
  const float gam = gamma[0];
#pragma unroll
  for (int i = 0; i < 16; ++i) {
    const int q = qs + i;
    const size_t idx = (size_t)c * NTOK + qb * 64 + q;
    out[idx] = gam * tile[q][c] * linv[q] + x[idx];
  }
}

extern "C" void kernel_launch(void* const* d_in, const int* in_sizes, int n_in,
                              void* d_out, int out_size, void* d_ws, size_t ws_size,
                              hipStream_t stream) {
  const float* x     = (const float*)d_in[0];
  const float* Wq    = (const float*)d_in[1];
  const float* bq    = (const float*)d_in[2];
  const float* Wk    = (const float*)d_in[3];
  const float* bk    = (const float*)d_in[4];
  const float* Wv    = (const float*)d_in[5];
  const float* bv    = (const float*)d_in[6];
  const float* gamma = (const float*)d_in[7];
  float* out = (float*)d_out;

  short* Qp = (short*)d_ws;                 // [N][8]  bf16  (256 KB)
  short* Kp = Qp + (size_t)NTOK * 8;        // [N][8]  bf16  (256 KB)
  short* Vp = Kp + (size_t)NTOK * 8;        // [64][N] bf16  (2 MB), permuted cols
  float* part  = (float*)(Vp + (size_t)64 * NTOK);       // [s][q][64c]

  const size_t base_bytes = (size_t)NTOK * 8 * 2 * 2 + (size_t)64 * NTOK * 2;
  auto fits = [&](int sp) {
    return base_bytes + (size_t)sp * NTOK * 64 * 4 + (size_t)sp * NTOK * 4 <= ws_size;
  };

  // target >= 4096 waves (4/SIMD): NF=4 needs splits=16; NF=2 needs splits=8.
  int NF, splits;
  if (fits(16))      { NF = 4; splits = 16; }
  else if (fits(8))  { NF = 2; splits = 8;  }
  else               { NF = 2; splits = 4; if (!fits(4)) splits = 2; }

  float* lsums = part + (size_t)splits * NTOK * 64;

  proj_qk_kernel<<<dim3(NTOK / 256, 2), 256, 0, stream>>>(x, Wq, bq, Wk, bk, Qp, Kp);
  proj_v_kernel<<<dim3(NTOK / 256, 4), 256, 0, stream>>>(x, Wv, bv, Vp);
  const int nqw = NTOK / (NF * 16);
  if (NF == 4)
    attn_split_kernel<4><<<dim3(splits, nqw / 4), 256, 0, stream>>>(Qp, Kp, Vp, part, lsums, splits);
  else
    attn_split_kernel<2><<<dim3(splits, nqw / 4), 256, 0, stream>>>(Qp, Kp, Vp, part, lsums, splits);
  reduce_kernel<<<NTOK / 64, 256, 0, stream>>>(part, lsums, x, gamma, out, splits);
}